// Round 4
// baseline (331.609 us; speedup 1.0000x reference)
//
#include <hip/hip_runtime.h>
#include <hip/hip_bf16.h>

typedef unsigned short u16;
using short8 = __attribute__((ext_vector_type(8))) short;
using f32x4  = __attribute__((ext_vector_type(4))) float;

#define IN_FEAT  4096
#define OUT_FEAT 4096
#define BATCH    2048
// packed triangular B: group g (128 rows) has row length (g+1)*128 u16;
// group base = 16384 * g*(g+1)/2; total = 16384 * 528 u16 per matrix.
#define BPACK    8650752

// direct global->LDS, 16B per lane; LDS dest is wave-uniform base + lane*16
#define GLOAD16(gp, lp)                                                        \
    __builtin_amdgcn_global_load_lds(                                          \
        (__attribute__((address_space(1))) void*)(gp),                         \
        (__attribute__((address_space(3))) void*)(lp), 16, 0, 0)

// ---------------------------------------------------------------------------
// Kernel 1: split x (f32) into bf16 hi + lo residual.
// ---------------------------------------------------------------------------
__global__ __launch_bounds__(256) void split_x(const float* __restrict__ x,
                                               u16* __restrict__ xhi,
                                               u16* __restrict__ xlo)
{
    const int n4 = (BATCH * IN_FEAT) / 4;
    for (int i = blockIdx.x * blockDim.x + threadIdx.x; i < n4;
         i += gridDim.x * blockDim.x) {
        float4 v = ((const float4*)x)[i];
        float vv[4] = {v.x, v.y, v.z, v.w};
        u16 hh[4], ll[4];
#pragma unroll
        for (int k = 0; k < 4; ++k) {
            __hip_bfloat16 hb = __float2bfloat16(vv[k]);
            float hf = __bfloat162float(hb);
            __hip_bfloat16 lb = __float2bfloat16(vv[k] - hf);
            hh[k] = *(u16*)&hb;
            ll[k] = *(u16*)&lb;
        }
        ushort4 h, l;
        h.x = hh[0]; h.y = hh[1]; h.z = hh[2]; h.w = hh[3];
        l.x = ll[0]; l.y = ll[1]; l.z = ll[2]; l.w = ll[3];
        ((ushort4*)xhi)[i] = h;
        ((ushort4*)xlo)[i] = l;
    }
}

// ---------------------------------------------------------------------------
// Kernel 2: per output row o (group g = o/128, block r = o/32):
//   Wm = exp(W) on diag block, W on strict-lower; norm over active K;
//   Wn = exp(ls)*Wm/norm -> bf16 hi/lo, packed triangular, zero-padded to
//   kpad=(g+1)*128; log of diag 32x32 block -> jac output.
// ---------------------------------------------------------------------------
__global__ __launch_bounds__(256) void prep_w(const float* __restrict__ W,
                                              const float* __restrict__ wls,
                                              u16* __restrict__ bhi,
                                              u16* __restrict__ blo,
                                              float* __restrict__ jac)
{
    const int o    = blockIdx.x;          // 0..4095
    const int r    = o >> 5;              // 32-block row index
    const int g    = o >> 7;              // 128-group index (= GEMM N-tile j)
    const int kact = (r + 1) * 32;        // active K for this row
    const int kpad = (g + 1) << 7;        // packed row length
    const int dlo  = r * 32;              // diag block col start

    __shared__ float rowbuf[4096];
    __shared__ float red[4];

    // pass 1: masked transform + sum of squares (vectorized f32x4 reads)
    const float* wrow = W + (size_t)o * IN_FEAT;
    float ss = 0.f;
    const int k4 = kact >> 2;
    for (int c4 = threadIdx.x; c4 < k4; c4 += 256) {
        float4 wv = ((const float4*)wrow)[c4];
        float vv[4] = {wv.x, wv.y, wv.z, wv.w};
        const int c = c4 * 4;
#pragma unroll
        for (int e = 0; e < 4; ++e) {
            float wm = (c + e >= dlo) ? expf(vv[e]) : vv[e];
            rowbuf[c + e] = wm;
            ss += wm * wm;
        }
    }
    for (int off = 32; off > 0; off >>= 1) ss += __shfl_down(ss, off, 64);
    const int lane = threadIdx.x & 63, wid = threadIdx.x >> 6;
    if (lane == 0) red[wid] = ss;
    __syncthreads();
    const float total = red[0] + red[1] + red[2] + red[3];
    const float scale = expf(wls[o]) / sqrtf(total);

    // pass 2: scale, split to bf16 hi/lo (short8 stores, packed), jac logs
    const size_t rowbase = (size_t)16384 * ((size_t)g * (g + 1) / 2)
                         + (size_t)(o & 127) * kpad;
    u16* bh = bhi + rowbase;
    u16* bl = blo + rowbase;
    for (int c0 = threadIdx.x * 8; c0 < kpad; c0 += 2048) {
        short8 hv, lv;
#pragma unroll
        for (int e = 0; e < 8; ++e) {
            const int c = c0 + e;
            float wn = (c < kact) ? rowbuf[c] * scale : 0.f;
            __hip_bfloat16 h = __float2bfloat16(wn);
            float hf = __bfloat162float(h);
            __hip_bfloat16 l = __float2bfloat16(wn - hf);
            hv[e] = *(short*)&h;
            lv[e] = *(short*)&l;
            if (c >= dlo && c < kact)
                jac[(size_t)r * 1024 + (size_t)(o & 31) * 32 + (c - dlo)] =
                    logf(wn);
        }
        *(short8*)(bh + c0) = hv;
        *(short8*)(bl + c0) = lv;
    }
}

// ---------------------------------------------------------------------------
// Kernel 3: y[b,o] = sum_k x[b,k]*Wn[o,k] + bias[o]  (NT GEMM, bf16x3 split)
// 128x128 tile, BK=32, 4 waves in 2x2 (64x64 each), mfma_f32_16x16x32_bf16.
// Per K-step: wave w stages one of {Ahi,Alo,Bhi,Blo} via global_load_lds x8.
// K extent per N-tile j is (j+1)*128 (block-lower-triangular Wn); B is
// packed triangular (row stride = ksteps*32 u16, base = 16384*j(j+1)/2).
//
// LDS swizzle (rule #21: both-sides-or-neither):
//   LDS slot (row, s) holds global k-group s ^ ((row>>1)&3):
//   write side: LDS dest linear (global_load_lds), global source col-group
//               pre-swizzled: (l&3)^((l>>3)&3)   [row = 16t + (l>>2)]
//   read side:  slot = kq ^ ((fr>>1)&3)  -> contents = logical kq. Involution.
//   Bank check: per 8-lane b128 phase (fixed kq, fr=0..7),
//   quad = (4*fr + slot) mod 8 covers all 8 -> conflict-free (was 8-way).
// ---------------------------------------------------------------------------
__global__ __launch_bounds__(256, 2) void gemm_bar(
    const u16* __restrict__ xhi, const u16* __restrict__ xlo,
    const u16* __restrict__ bhi, const u16* __restrict__ blo,
    const float* __restrict__ bias, float* __restrict__ y)
{
    __shared__ __align__(16) u16 As_hi[128][32];
    __shared__ __align__(16) u16 As_lo[128][32];
    __shared__ __align__(16) u16 Bs_hi[128][32];
    __shared__ __align__(16) u16 Bs_lo[128][32];

    // Heavy-tiles-first (LPT) dispatch: first 256 blocks are j=16..31.
    const int bid = blockIdx.x;          // 0..511
    const int jj  = bid >> 4;            // 0..31
    const int j   = (jj < 16) ? (31 - jj) : (jj - 16);
    const int i   = bid & 15;
    const int bm0 = i * 128;
    const int bn0 = j * 128;
    const int ksteps = (j + 1) * 4;      // K = (j+1)*128, BK=32

    const int tid  = threadIdx.x;
    const int w    = tid >> 6;
    const int lane = tid & 63;
    const int wm   = (w & 1) * 64;       // wave's M offset in tile
    const int wn   = (w >> 1) * 64;      // wave's N offset in tile
    const int fr   = lane & 15;          // fragment row
    const int kq   = lane >> 4;          // fragment k-group (0..3)
    const int kcg  = (kq ^ ((fr >> 1) & 3)) * 8;             // swizzled read col (u16)
    const int srr  = lane >> 2;                              // staging row in 16-chunk
    const int scb  = ((lane & 3) ^ ((lane >> 3) & 3)) * 8;   // pre-swz src col (u16)

    // staging assignment per wave
    const u16* gbase;     // already offset to this tile's row 0
    size_t gstride;       // u16 per row
    u16* ldst;
    if (w == 0) {
        gbase = xhi + (size_t)bm0 * IN_FEAT; gstride = IN_FEAT;
        ldst  = &As_hi[0][0];
    } else if (w == 1) {
        gbase = xlo + (size_t)bm0 * IN_FEAT; gstride = IN_FEAT;
        ldst  = &As_lo[0][0];
    } else {
        const size_t pbase = (size_t)16384 * ((size_t)j * (j + 1) / 2);
        gstride = (size_t)ksteps * 32;
        if (w == 2) { gbase = bhi + pbase; ldst = &Bs_hi[0][0]; }
        else        { gbase = blo + pbase; ldst = &Bs_lo[0][0]; }
    }

    f32x4 acc[4][4];
#pragma unroll
    for (int a = 0; a < 4; ++a)
#pragma unroll
        for (int b = 0; b < 4; ++b)
            acc[a][b] = (f32x4){0.f, 0.f, 0.f, 0.f};

    for (int kt = 0; kt < ksteps; ++kt) {
        const int kbase = kt * 32;
#pragma unroll
        for (int t = 0; t < 8; ++t) {
            const u16* g = gbase + (size_t)(t * 16 + srr) * gstride
                                 + kbase + scb;
            GLOAD16(g, ldst + t * 16 * 32);
        }
        __syncthreads();

        short8 ah[4], al[4], bh[4], bl[4];
#pragma unroll
        for (int mi = 0; mi < 4; ++mi) {
            const int row = wm + mi * 16 + fr;
            ah[mi] = *(const short8*)(&As_hi[0][0] + row * 32 + kcg);
            al[mi] = *(const short8*)(&As_lo[0][0] + row * 32 + kcg);
        }
#pragma unroll
        for (int ni = 0; ni < 4; ++ni) {
            const int row = wn + ni * 16 + fr;
            bh[ni] = *(const short8*)(&Bs_hi[0][0] + row * 32 + kcg);
            bl[ni] = *(const short8*)(&Bs_lo[0][0] + row * 32 + kcg);
        }
#pragma unroll
        for (int mi = 0; mi < 4; ++mi)
#pragma unroll
            for (int ni = 0; ni < 4; ++ni) {
                f32x4 c = acc[mi][ni];
                c = __builtin_amdgcn_mfma_f32_16x16x32_bf16(ah[mi], bh[ni], c, 0, 0, 0);
                c = __builtin_amdgcn_mfma_f32_16x16x32_bf16(ah[mi], bl[ni], c, 0, 0, 0);
                c = __builtin_amdgcn_mfma_f32_16x16x32_bf16(al[mi], bh[ni], c, 0, 0, 0);
                acc[mi][ni] = c;
            }
        __syncthreads();
    }

    // epilogue: C/D layout col=lane&15 (B-side n), row=(lane>>4)*4+q (A-side m)
    const int crow = (lane >> 4) * 4;
    const int ccol = lane & 15;
#pragma unroll
    for (int ni = 0; ni < 4; ++ni) {
        const int n = bn0 + wn + ni * 16 + ccol;
        const float bv = bias[n];
#pragma unroll
        for (int mi = 0; mi < 4; ++mi) {
#pragma unroll
            for (int q = 0; q < 4; ++q) {
                const int m = bm0 + wm + mi * 16 + crow + q;
                y[(size_t)m * 4096 + n] = acc[mi][ni][q] + bv;
            }
        }
    }
}

// ---------------------------------------------------------------------------
extern "C" void kernel_launch(void* const* d_in, const int* in_sizes, int n_in,
                              void* d_out, int out_size, void* d_ws, size_t ws_size,
                              hipStream_t stream)
{
    const float* x    = (const float*)d_in[0];
    const float* W    = (const float*)d_in[1];
    const float* bias = (const float*)d_in[2];
    const float* wls  = (const float*)d_in[3];
    // d_in[4], d_in[5] (masks) are not read: mask structure derived from indices.

    // workspace layout: packed-B hi/lo (2 x 16.5 MiB) + X hi/lo (2 x 16 MiB)
    const size_t need = ((size_t)BPACK * 2 + (size_t)BATCH * IN_FEAT * 2)
                        * sizeof(u16);   // 68,157,440 B
    if (ws_size < need) return;  // clean failure signal (output stays poisoned)

    u16* Bhi = (u16*)d_ws;
    u16* Blo = Bhi + (size_t)BPACK;
    u16* Xhi = Blo + (size_t)BPACK;
    u16* Xlo = Xhi + (size_t)BATCH * IN_FEAT;

    float* y   = (float*)d_out;
    float* jac = y + (size_t)BATCH * OUT_FEAT;   // 128*32*32 floats

    split_x<<<2048, 256, 0, stream>>>(x, Xhi, Xlo);
    prep_w<<<4096, 256, 0, stream>>>(W, wls, Bhi, Blo, jac);
    gemm_bar<<<512, 256, 0, stream>>>(Xhi, Xlo, Bhi, Blo, bias, y);
}

// Round 5
// 316.793 us; speedup vs baseline: 1.0468x; 1.0468x over previous
//
#include <hip/hip_runtime.h>
#include <hip/hip_bf16.h>

typedef unsigned short u16;
using short8 = __attribute__((ext_vector_type(8))) short;
using f32x4  = __attribute__((ext_vector_type(4))) float;

#define IN_FEAT  4096
#define OUT_FEAT 4096
#define BATCH    2048
// packed triangular B: group g (128 rows) has row length (g+1)*128 u16;
// group base = 16384 * g*(g+1)/2; total = 16384 * 528 u16 per matrix.
#define BPACK    8650752

// direct global->LDS, 16B per lane; LDS dest is wave-uniform base + lane*16
#define GLOAD16(gp, lp)                                                        \
    __builtin_amdgcn_global_load_lds(                                          \
        (__attribute__((address_space(1))) void*)(gp),                         \
        (__attribute__((address_space(3))) void*)(lp), 16, 0, 0)

// ---------------------------------------------------------------------------
// Merged prep kernel (one dispatch => clean duration attribution):
//   blocks [0, 4096):    W-row prep, LPT order (heavy rows o=4095.. first)
//   blocks [4096, 6144): x split into bf16 hi/lo
// ---------------------------------------------------------------------------
__global__ __launch_bounds__(256) void prep(const float* __restrict__ x,
                                            const float* __restrict__ W,
                                            const float* __restrict__ wls,
                                            u16* __restrict__ xhi,
                                            u16* __restrict__ xlo,
                                            u16* __restrict__ bhi,
                                            u16* __restrict__ blo,
                                            float* __restrict__ jac)
{
    __shared__ float rowbuf[4096];
    __shared__ float red[4];

    if (blockIdx.x >= 4096) {
        // ---- x split part ----
        const int bid = blockIdx.x - 4096;
        const int n4 = (BATCH * IN_FEAT) / 4;
        for (int i = bid * 256 + threadIdx.x; i < n4; i += 2048 * 256) {
            float4 v = ((const float4*)x)[i];
            float vv[4] = {v.x, v.y, v.z, v.w};
            u16 hh[4], ll[4];
#pragma unroll
            for (int k = 0; k < 4; ++k) {
                __hip_bfloat16 hb = __float2bfloat16(vv[k]);
                float hf = __bfloat162float(hb);
                __hip_bfloat16 lb = __float2bfloat16(vv[k] - hf);
                hh[k] = *(u16*)&hb;
                ll[k] = *(u16*)&lb;
            }
            ushort4 h, l;
            h.x = hh[0]; h.y = hh[1]; h.z = hh[2]; h.w = hh[3];
            l.x = ll[0]; l.y = ll[1]; l.z = ll[2]; l.w = ll[3];
            ((ushort4*)xhi)[i] = h;
            ((ushort4*)xlo)[i] = l;
        }
        return;
    }

    // ---- W-row prep part ----
    const int o    = 4095 - blockIdx.x;   // heavy rows first (LPT)
    const int r    = o >> 5;              // 32-block row index
    const int g    = o >> 7;              // 128-group index (= GEMM N-tile j)
    const int kact = (r + 1) * 32;        // active K for this row
    const int kpad = (g + 1) << 7;        // packed row length
    const int dlo  = r * 32;              // diag block col start

    // pass 1: masked transform + sum of squares (vectorized f32x4 reads)
    const float* wrow = W + (size_t)o * IN_FEAT;
    float ss = 0.f;
    const int k4 = kact >> 2;
    for (int c4 = threadIdx.x; c4 < k4; c4 += 256) {
        float4 wv = ((const float4*)wrow)[c4];
        float vv[4] = {wv.x, wv.y, wv.z, wv.w};
        const int c = c4 * 4;
#pragma unroll
        for (int e = 0; e < 4; ++e) {
            float wm = (c + e >= dlo) ? expf(vv[e]) : vv[e];
            rowbuf[c + e] = wm;
            ss += wm * wm;
        }
    }
    for (int off = 32; off > 0; off >>= 1) ss += __shfl_down(ss, off, 64);
    const int lane = threadIdx.x & 63, wid = threadIdx.x >> 6;
    if (lane == 0) red[wid] = ss;
    __syncthreads();
    const float total = red[0] + red[1] + red[2] + red[3];
    const float scale = expf(wls[o]) / sqrtf(total);

    // pass 2: scale, split to bf16 hi/lo (short8 stores, packed), jac logs
    const size_t rowbase = (size_t)16384 * ((size_t)g * (g + 1) / 2)
                         + (size_t)(o & 127) * kpad;
    u16* bh = bhi + rowbase;
    u16* bl = blo + rowbase;
    for (int c0 = threadIdx.x * 8; c0 < kpad; c0 += 2048) {
        short8 hv, lv;
#pragma unroll
        for (int e = 0; e < 8; ++e) {
            const int c = c0 + e;
            float wn = (c < kact) ? rowbuf[c] * scale : 0.f;
            __hip_bfloat16 h = __float2bfloat16(wn);
            float hf = __bfloat162float(h);
            __hip_bfloat16 l = __float2bfloat16(wn - hf);
            hv[e] = *(short*)&h;
            lv[e] = *(short*)&l;
            if (c >= dlo && c < kact)
                jac[(size_t)r * 1024 + (size_t)(o & 31) * 32 + (c - dlo)] =
                    logf(wn);
        }
        *(short8*)(bh + c0) = hv;
        *(short8*)(bl + c0) = lv;
    }
}

// ---------------------------------------------------------------------------
// Kernel 2: y[b,o] = sum_k x[b,k]*Wn[o,k] + bias[o]  (NT GEMM, bf16x3 split)
// 128x128 tile, BK=32, 4 waves in 2x2 (64x64 each), mfma_f32_16x16x32_bf16.
// 2-PHASE double-buffered pipeline (T3 minimum, §5.5): per K-step, issue
// next step's 8 global_load_lds into buf[cur^1] BEFORE ds_read+MFMA of
// buf[cur]; single __syncthreads per step (its vmcnt(0)+lgkmcnt(0) drain IS
// the 2-phase completion wait, overlapped with compute). WAR-safe: iter kt's
// stage targets buf[cur^1], last read by iter kt-1 whose ds_reads drain at
// its own barrier (lgkmcnt(0)).
//
// LDS swizzle (rule #21, verified R2-R4, bank-conflict counter = 0):
//   slot (row, s) holds k-group s ^ ((row>>1)&3); write side via pre-swizzled
//   global col-group (l&3)^((l>>3)&3); read side slot = kq ^ ((fr>>1)&3).
// ---------------------------------------------------------------------------
__global__ __launch_bounds__(256, 2) void gemm_bar(
    const u16* __restrict__ xhi, const u16* __restrict__ xlo,
    const u16* __restrict__ bhi, const u16* __restrict__ blo,
    const float* __restrict__ bias, float* __restrict__ y)
{
    __shared__ __align__(16) u16 As_hi[2][128][32];
    __shared__ __align__(16) u16 As_lo[2][128][32];
    __shared__ __align__(16) u16 Bs_hi[2][128][32];
    __shared__ __align__(16) u16 Bs_lo[2][128][32];

    // Heavy-tiles-first dispatch; pair (bid, bid+256) lands on same CU and
    // sums to 33 K-units (balanced).
    const int bid = blockIdx.x;          // 0..511
    const int jj  = bid >> 4;            // 0..31
    const int j   = (jj < 16) ? (31 - jj) : (jj - 16);
    const int i   = bid & 15;
    const int bm0 = i * 128;
    const int bn0 = j * 128;
    const int ksteps = (j + 1) * 4;      // K = (j+1)*128, BK=32

    const int tid  = threadIdx.x;
    const int w    = tid >> 6;
    const int lane = tid & 63;
    const int wm   = (w & 1) * 64;       // wave's M offset in tile
    const int wn   = (w >> 1) * 64;      // wave's N offset in tile
    const int fr   = lane & 15;          // fragment row
    const int kq   = lane >> 4;          // fragment k-group (0..3)
    const int kcg  = (kq ^ ((fr >> 1) & 3)) * 8;             // swizzled read col (u16)
    const int srr  = lane >> 2;                              // staging row in 16-chunk
    const int scb  = ((lane & 3) ^ ((lane >> 3) & 3)) * 8;   // pre-swz src col (u16)

    // staging assignment per wave (each wave owns one of the 4 tiles)
    const u16* gbase;     // tile row 0 in global
    size_t gstride;       // u16 per row
    u16* ldst0;           // buffer-0 LDS base for this wave
    if (w == 0) {
        gbase = xhi + (size_t)bm0 * IN_FEAT; gstride = IN_FEAT;
        ldst0 = &As_hi[0][0][0];
    } else if (w == 1) {
        gbase = xlo + (size_t)bm0 * IN_FEAT; gstride = IN_FEAT;
        ldst0 = &As_lo[0][0][0];
    } else {
        const size_t pbase = (size_t)16384 * ((size_t)j * (j + 1) / 2);
        gstride = (size_t)ksteps * 32;
        if (w == 2) { gbase = bhi + pbase; ldst0 = &Bs_hi[0][0][0]; }
        else        { gbase = blo + pbase; ldst0 = &Bs_lo[0][0][0]; }
    }

    f32x4 acc[4][4];
#pragma unroll
    for (int a = 0; a < 4; ++a)
#pragma unroll
        for (int b = 0; b < 4; ++b)
            acc[a][b] = (f32x4){0.f, 0.f, 0.f, 0.f};

#define STAGE(buf, kt)                                                         \
    do {                                                                       \
        const int _kb = (kt) * 32;                                             \
        u16* _dst = ldst0 + (buf) * 4096;                                      \
        _Pragma("unroll")                                                      \
        for (int _t = 0; _t < 8; ++_t) {                                       \
            const u16* _g = gbase + (size_t)(_t * 16 + srr) * gstride          \
                                  + _kb + scb;                                 \
            GLOAD16(_g, _dst + _t * 512);                                      \
        }                                                                      \
    } while (0)

    STAGE(0, 0);
    __syncthreads();                     // buf0 staged (vmcnt(0) drain)

    int cur = 0;
    for (int kt = 0; kt < ksteps; ++kt) {
        if (kt + 1 < ksteps) STAGE(cur ^ 1, kt + 1);   // prefetch next step

        const int cb = cur * 4096;       // u16 offset of current buffer
        short8 ah[4], al[4], bh[4], bl[4];
#pragma unroll
        for (int mi = 0; mi < 4; ++mi) {
            const int row = wm + mi * 16 + fr;
            ah[mi] = *(const short8*)(&As_hi[0][0][0] + cb + row * 32 + kcg);
            al[mi] = *(const short8*)(&As_lo[0][0][0] + cb + row * 32 + kcg);
        }
#pragma unroll
        for (int ni = 0; ni < 4; ++ni) {
            const int row = wn + ni * 16 + fr;
            bh[ni] = *(const short8*)(&Bs_hi[0][0][0] + cb + row * 32 + kcg);
            bl[ni] = *(const short8*)(&Bs_lo[0][0][0] + cb + row * 32 + kcg);
        }
#pragma unroll
        for (int mi = 0; mi < 4; ++mi)
#pragma unroll
            for (int ni = 0; ni < 4; ++ni) {
                f32x4 c = acc[mi][ni];
                c = __builtin_amdgcn_mfma_f32_16x16x32_bf16(ah[mi], bh[ni], c, 0, 0, 0);
                c = __builtin_amdgcn_mfma_f32_16x16x32_bf16(ah[mi], bl[ni], c, 0, 0, 0);
                c = __builtin_amdgcn_mfma_f32_16x16x32_bf16(al[mi], bh[ni], c, 0, 0, 0);
                acc[mi][ni] = c;
            }
        __syncthreads();   // drains this wave's stage (vmcnt(0)) + ds_reads
        cur ^= 1;
    }
#undef STAGE

    // epilogue: C/D layout col=lane&15 (B-side n), row=(lane>>4)*4+q (A-side m)
    const int crow = (lane >> 4) * 4;
    const int ccol = lane & 15;
#pragma unroll
    for (int ni = 0; ni < 4; ++ni) {
        const int n = bn0 + wn + ni * 16 + ccol;
        const float bv = bias[n];
#pragma unroll
        for (int mi = 0; mi < 4; ++mi) {
#pragma unroll
            for (int q = 0; q < 4; ++q) {
                const int m = bm0 + wm + mi * 16 + crow + q;
                y[(size_t)m * 4096 + n] = acc[mi][ni][q] + bv;
            }
        }
    }
}

// ---------------------------------------------------------------------------
extern "C" void kernel_launch(void* const* d_in, const int* in_sizes, int n_in,
                              void* d_out, int out_size, void* d_ws, size_t ws_size,
                              hipStream_t stream)
{
    const float* x    = (const float*)d_in[0];
    const float* W    = (const float*)d_in[1];
    const float* bias = (const float*)d_in[2];
    const float* wls  = (const float*)d_in[3];
    // d_in[4], d_in[5] (masks) are not read: mask structure derived from indices.

    // workspace layout: packed-B hi/lo (2 x 16.5 MiB) + X hi/lo (2 x 16 MiB)
    const size_t need = ((size_t)BPACK * 2 + (size_t)BATCH * IN_FEAT * 2)
                        * sizeof(u16);   // 68,157,440 B
    if (ws_size < need) return;  // clean failure signal (output stays poisoned)

    u16* Bhi = (u16*)d_ws;
    u16* Blo = Bhi + (size_t)BPACK;
    u16* Xhi = Blo + (size_t)BPACK;
    u16* Xlo = Xhi + (size_t)BATCH * IN_FEAT;

    float* y   = (float*)d_out;
    float* jac = y + (size_t)BATCH * OUT_FEAT;   // 128*32*32 floats

    prep<<<6144, 256, 0, stream>>>(x, W, wls, Xhi, Xlo, Bhi, Blo, jac);
    gemm_bar<<<512, 256, 0, stream>>>(Xhi, Xlo, Bhi, Blo, bias, y);
}

// Round 6
// 310.260 us; speedup vs baseline: 1.0688x; 1.0211x over previous
//
#include <hip/hip_runtime.h>
#include <hip/hip_bf16.h>

typedef unsigned short u16;
using short8 = __attribute__((ext_vector_type(8))) short;
using f32x4  = __attribute__((ext_vector_type(4))) float;

#define IN_FEAT  4096
#define OUT_FEAT 4096
#define BATCH    2048
// packed triangular B: group g (128 rows) has row length (g+1)*128 u16;
// group base = 16384 * g*(g+1)/2; total = 16384 * 528 u16 per matrix.
#define BPACK    8650752

// direct global->LDS, 16B per lane; LDS dest is wave-uniform base + lane*16
#define GLOAD16(gp, lp)                                                        \
    __builtin_amdgcn_global_load_lds(                                          \
        (__attribute__((address_space(1))) void*)(gp),                         \
        (__attribute__((address_space(3))) void*)(lp), 16, 0, 0)

// ---------------------------------------------------------------------------
// Kernel 1: split x (f32) into bf16 hi + lo residual. 16B/lane both ways.
// ---------------------------------------------------------------------------
__global__ __launch_bounds__(256) void split_x(const float* __restrict__ x,
                                               u16* __restrict__ xhi,
                                               u16* __restrict__ xlo)
{
    const int n8 = (BATCH * IN_FEAT) / 8;
    for (int i = blockIdx.x * blockDim.x + threadIdx.x; i < n8;
         i += gridDim.x * blockDim.x) {
        float4 a = ((const float4*)x)[2 * i];
        float4 b = ((const float4*)x)[2 * i + 1];
        float vv[8] = {a.x, a.y, a.z, a.w, b.x, b.y, b.z, b.w};
        short8 h, l;
#pragma unroll
        for (int k = 0; k < 8; ++k) {
            __hip_bfloat16 hb = __float2bfloat16(vv[k]);
            float hf = __bfloat162float(hb);
            __hip_bfloat16 lb = __float2bfloat16(vv[k] - hf);
            h[k] = *(short*)&hb;
            l[k] = *(short*)&lb;
        }
        ((short8*)xhi)[i] = h;
        ((short8*)xlo)[i] = l;
    }
}

// ---------------------------------------------------------------------------
// Kernel 2: per output row o (group g = o/128, block r = o/32):
//   Wm = exp(W) on diag block, W on strict-lower; norm over active K;
//   Wn = exp(ls)*Wm/norm -> bf16 hi/lo, packed triangular, zero-padded to
//   kpad=(g+1)*128; log of diag 32x32 block -> jac (separate 32-thread pass).
// ---------------------------------------------------------------------------
__global__ __launch_bounds__(256) void prep_w(const float* __restrict__ W,
                                              const float* __restrict__ wls,
                                              u16* __restrict__ bhi,
                                              u16* __restrict__ blo,
                                              float* __restrict__ jac)
{
    const int o    = 4095 - blockIdx.x;   // heavy rows first (LPT)
    const int r    = o >> 5;              // 32-block row index
    const int g    = o >> 7;              // 128-group index (= GEMM N-tile j)
    const int kact = (r + 1) * 32;        // active K for this row
    const int kpad = (g + 1) << 7;        // packed row length
    const int dlo  = r * 32;              // diag block col start

    __shared__ float rowbuf[4096];
    __shared__ float red[4];

    // pass 1: masked transform + sum of squares (f32x4 in, f32x4 LDS out)
    const float* wrow = W + (size_t)o * IN_FEAT;
    float ss = 0.f;
    const int k4 = kact >> 2;
    for (int c4 = threadIdx.x; c4 < k4; c4 += 256) {
        float4 wv = ((const float4*)wrow)[c4];
        f32x4 out;
        float vv[4] = {wv.x, wv.y, wv.z, wv.w};
        const int c = c4 * 4;
#pragma unroll
        for (int e = 0; e < 4; ++e) {
            float wm = (c + e >= dlo) ? __expf(vv[e]) : vv[e];
            out[e] = wm;
            ss += wm * wm;
        }
        *(f32x4*)&rowbuf[c] = out;
    }
    for (int off = 32; off > 0; off >>= 1) ss += __shfl_down(ss, off, 64);
    const int lane = threadIdx.x & 63, wid = threadIdx.x >> 6;
    if (lane == 0) red[wid] = ss;
    __syncthreads();
    const float total = red[0] + red[1] + red[2] + red[3];
    const float scale = expf(wls[o]) / sqrtf(total);

    // pass 2: scale + bf16 hi/lo split, 16B stores, packed layout
    const size_t rowbase = (size_t)16384 * ((size_t)g * (g + 1) / 2)
                         + (size_t)(o & 127) * kpad;
    u16* bh = bhi + rowbase;
    u16* bl = blo + rowbase;
    for (int c0 = threadIdx.x * 8; c0 < kpad; c0 += 2048) {
        short8 hv, lv;
        if (c0 + 8 <= kact) {
            f32x4 w0 = *(const f32x4*)&rowbuf[c0];
            f32x4 w1 = *(const f32x4*)&rowbuf[c0 + 4];
            float vv[8] = {w0[0], w0[1], w0[2], w0[3],
                           w1[0], w1[1], w1[2], w1[3]};
#pragma unroll
            for (int e = 0; e < 8; ++e) {
                float wn = vv[e] * scale;
                __hip_bfloat16 h = __float2bfloat16(wn);
                float hf = __bfloat162float(h);
                __hip_bfloat16 l = __float2bfloat16(wn - hf);
                hv[e] = *(short*)&h;
                lv[e] = *(short*)&l;
            }
        } else {
#pragma unroll
            for (int e = 0; e < 8; ++e) {
                const int c = c0 + e;
                float wn = (c < kact) ? rowbuf[c] * scale : 0.f;
                __hip_bfloat16 h = __float2bfloat16(wn);
                float hf = __bfloat162float(h);
                __hip_bfloat16 l = __float2bfloat16(wn - hf);
                hv[e] = *(short*)&h;
                lv[e] = *(short*)&l;
            }
        }
        *(short8*)(bh + c0) = hv;
        *(short8*)(bl + c0) = lv;
    }

    // pass 3: jac = log(diag 32 window), one thread per column
    if (threadIdx.x < 32)
        jac[(size_t)r * 1024 + (size_t)(o & 31) * 32 + threadIdx.x] =
            __logf(rowbuf[dlo + threadIdx.x] * scale);
}

// ---------------------------------------------------------------------------
// Kernel 3: y[b,o] = sum_k x[b,k]*Wn[o,k] + bias[o]  (NT GEMM, bf16x3 split)
// 128x128 tile, BK=32, 4 waves in 2x2 (64x64 each), mfma_f32_16x16x32_bf16.
// 2-PHASE double-buffered pipeline (T3 minimum, §5.5). Measured R5:
// 128.1 µs, MfmaUtil 35%, bank conflicts 0 -> at the 2-phase structural
// ceiling (~830 TF effective). FROZEN this round.
//
// LDS swizzle (rule #21, verified: SQ_LDS_BANK_CONFLICT = 0):
//   slot (row, s) holds k-group s ^ ((row>>1)&3); write side via pre-swizzled
//   global col-group (l&3)^((l>>3)&3); read side slot = kq ^ ((fr>>1)&3).
// ---------------------------------------------------------------------------
__global__ __launch_bounds__(256, 2) void gemm_bar(
    const u16* __restrict__ xhi, const u16* __restrict__ xlo,
    const u16* __restrict__ bhi, const u16* __restrict__ blo,
    const float* __restrict__ bias, float* __restrict__ y)
{
    __shared__ __align__(16) u16 As_hi[2][128][32];
    __shared__ __align__(16) u16 As_lo[2][128][32];
    __shared__ __align__(16) u16 Bs_hi[2][128][32];
    __shared__ __align__(16) u16 Bs_lo[2][128][32];

    // Heavy-tiles-first dispatch; pair (bid, bid+256) lands on same CU and
    // sums to 33 K-units (balanced).
    const int bid = blockIdx.x;          // 0..511
    const int jj  = bid >> 4;            // 0..31
    const int j   = (jj < 16) ? (31 - jj) : (jj - 16);
    const int i   = bid & 15;
    const int bm0 = i * 128;
    const int bn0 = j * 128;
    const int ksteps = (j + 1) * 4;      // K = (j+1)*128, BK=32

    const int tid  = threadIdx.x;
    const int w    = tid >> 6;
    const int lane = tid & 63;
    const int wm   = (w & 1) * 64;       // wave's M offset in tile
    const int wn   = (w >> 1) * 64;      // wave's N offset in tile
    const int fr   = lane & 15;          // fragment row
    const int kq   = lane >> 4;          // fragment k-group (0..3)
    const int kcg  = (kq ^ ((fr >> 1) & 3)) * 8;             // swizzled read col (u16)
    const int srr  = lane >> 2;                              // staging row in 16-chunk
    const int scb  = ((lane & 3) ^ ((lane >> 3) & 3)) * 8;   // pre-swz src col (u16)

    // staging assignment per wave (each wave owns one of the 4 tiles)
    const u16* gbase;     // tile row 0 in global
    size_t gstride;       // u16 per row
    u16* ldst0;           // buffer-0 LDS base for this wave
    if (w == 0) {
        gbase = xhi + (size_t)bm0 * IN_FEAT; gstride = IN_FEAT;
        ldst0 = &As_hi[0][0][0];
    } else if (w == 1) {
        gbase = xlo + (size_t)bm0 * IN_FEAT; gstride = IN_FEAT;
        ldst0 = &As_lo[0][0][0];
    } else {
        const size_t pbase = (size_t)16384 * ((size_t)j * (j + 1) / 2);
        gstride = (size_t)ksteps * 32;
        if (w == 2) { gbase = bhi + pbase; ldst0 = &Bs_hi[0][0][0]; }
        else        { gbase = blo + pbase; ldst0 = &Bs_lo[0][0][0]; }
    }

    f32x4 acc[4][4];
#pragma unroll
    for (int a = 0; a < 4; ++a)
#pragma unroll
        for (int b = 0; b < 4; ++b)
            acc[a][b] = (f32x4){0.f, 0.f, 0.f, 0.f};

#define STAGE(buf, kt)                                                         \
    do {                                                                       \
        const int _kb = (kt) * 32;                                             \
        u16* _dst = ldst0 + (buf) * 4096;                                      \
        _Pragma("unroll")                                                      \
        for (int _t = 0; _t < 8; ++_t) {                                       \
            const u16* _g = gbase + (size_t)(_t * 16 + srr) * gstride          \
                                  + _kb + scb;                                 \
            GLOAD16(_g, _dst + _t * 512);                                      \
        }                                                                      \
    } while (0)

    STAGE(0, 0);
    __syncthreads();                     // buf0 staged (vmcnt(0) drain)

    int cur = 0;
    for (int kt = 0; kt < ksteps; ++kt) {
        if (kt + 1 < ksteps) STAGE(cur ^ 1, kt + 1);   // prefetch next step

        const int cb = cur * 4096;       // u16 offset of current buffer
        short8 ah[4], al[4], bh[4], bl[4];
#pragma unroll
        for (int mi = 0; mi < 4; ++mi) {
            const int row = wm + mi * 16 + fr;
            ah[mi] = *(const short8*)(&As_hi[0][0][0] + cb + row * 32 + kcg);
            al[mi] = *(const short8*)(&As_lo[0][0][0] + cb + row * 32 + kcg);
        }
#pragma unroll
        for (int ni = 0; ni < 4; ++ni) {
            const int row = wn + ni * 16 + fr;
            bh[ni] = *(const short8*)(&Bs_hi[0][0][0] + cb + row * 32 + kcg);
            bl[ni] = *(const short8*)(&Bs_lo[0][0][0] + cb + row * 32 + kcg);
        }
#pragma unroll
        for (int mi = 0; mi < 4; ++mi)
#pragma unroll
            for (int ni = 0; ni < 4; ++ni) {
                f32x4 c = acc[mi][ni];
                c = __builtin_amdgcn_mfma_f32_16x16x32_bf16(ah[mi], bh[ni], c, 0, 0, 0);
                c = __builtin_amdgcn_mfma_f32_16x16x32_bf16(ah[mi], bl[ni], c, 0, 0, 0);
                c = __builtin_amdgcn_mfma_f32_16x16x32_bf16(al[mi], bh[ni], c, 0, 0, 0);
                acc[mi][ni] = c;
            }
        __syncthreads();   // drains this wave's stage (vmcnt(0)) + ds_reads
        cur ^= 1;
    }
#undef STAGE

    // epilogue: C/D layout col=lane&15 (B-side n), row=(lane>>4)*4+q (A-side m)
    const int crow = (lane >> 4) * 4;
    const int ccol = lane & 15;
#pragma unroll
    for (int ni = 0; ni < 4; ++ni) {
        const int n = bn0 + wn + ni * 16 + ccol;
        const float bv = bias[n];
#pragma unroll
        for (int mi = 0; mi < 4; ++mi) {
#pragma unroll
            for (int q = 0; q < 4; ++q) {
                const int m = bm0 + wm + mi * 16 + crow + q;
                y[(size_t)m * 4096 + n] = acc[mi][ni][q] + bv;
            }
        }
    }
}

// ---------------------------------------------------------------------------
extern "C" void kernel_launch(void* const* d_in, const int* in_sizes, int n_in,
                              void* d_out, int out_size, void* d_ws, size_t ws_size,
                              hipStream_t stream)
{
    const float* x    = (const float*)d_in[0];
    const float* W    = (const float*)d_in[1];
    const float* bias = (const float*)d_in[2];
    const float* wls  = (const float*)d_in[3];
    // d_in[4], d_in[5] (masks) are not read: mask structure derived from indices.

    // workspace layout: packed-B hi/lo (2 x 16.5 MiB) + X hi/lo (2 x 16 MiB)
    const size_t need = ((size_t)BPACK * 2 + (size_t)BATCH * IN_FEAT * 2)
                        * sizeof(u16);   // 68,157,440 B
    if (ws_size < need) return;  // clean failure signal (output stays poisoned)

    u16* Bhi = (u16*)d_ws;
    u16* Blo = Bhi + (size_t)BPACK;
    u16* Xhi = Blo + (size_t)BPACK;
    u16* Xlo = Xhi + (size_t)BATCH * IN_FEAT;

    float* y   = (float*)d_out;
    float* jac = y + (size_t)BATCH * OUT_FEAT;   // 128*32*32 floats

    split_x<<<1024, 256, 0, stream>>>(x, Xhi, Xlo);
    prep_w<<<4096, 256, 0, stream>>>(W, wls, Bhi, Blo, jac);
    gemm_bar<<<512, 256, 0, stream>>>(Xhi, Xlo, Bhi, Blo, bias, y);
}